// Round 1
// baseline (843.038 us; speedup 1.0000x reference)
//
#include <hip/hip_runtime.h>

#define NN 50000
#define NE 400000
#define NG (NN / 16)        // 3125 groups of 16 consecutive src nodes
#define CAP 320             // bucket capacity: mean 128, sigma 11.3 -> 17-sigma margin
#define YSTRIDE 276         // 272 + pad (b128 align, spreads banks)

// ws layout (4B words):
//   agg1    float [16*NN]          zeroed
//   agg2    float [16*NN]          zeroed
//   cursor  int   [NG]             zeroed (per-group edge count)
//   cnt_dst int   [NN]             zeroed (in-degree, mean denominator)
//   pad     int   [1]              (8B-align ord)
//   ord     int2  [NG*CAP]         {eid, dst | src_local<<27}
//   h1      float [16*NN]

// ---------------------------------------------------------------------------
// One pass over edges: bucket by src-group (fixed capacity, no scan needed)
// + dst in-degree histogram.
// ---------------------------------------------------------------------------
__global__ __launch_bounds__(256) void fill_hist_kernel(
    const int* __restrict__ eidx, int* __restrict__ cursor,
    int* __restrict__ cnt_dst, int2* __restrict__ ord)
{
    int e = blockIdx.x * 256 + threadIdx.x;
    if (e < NE) {
        int s = eidx[e], d = eidx[NE + e];
        atomicAdd(&cnt_dst[d], 1);
        int g = s >> 4;
        int slot = atomicAdd(&cursor[g], 1);
        if (slot < CAP)   // statistically impossible to overflow; guard anyway
            ord[(size_t)g * CAP + slot] = make_int2(e, d | ((s & 15) << 27));
    }
}

// ---------------------------------------------------------------------------
// Fused edge kernel. Block = group of 16 src nodes.
// SECOND=true: staging phase first computes h1 = relu(agg1/cnt + x@root1 + b1)
//              for its 16 nodes (each node belongs to exactly one group),
//              writes it to global once, and uses it as the layer input.
// Phase 1: Y[node][k][o] = sum_i in[node,i]*w2[k,i,o], Y0 (b2 term) at 256.
// Phase 2: thread per bucket slot: hid = relu(ea[e]@w1+b1);
//          msg = Y0 + sum_k hid[k]*Y[k]; 16x unsafeAtomicAdd into agg[dst].
// ---------------------------------------------------------------------------
template <bool SECOND>
__global__ __launch_bounds__(256) void edge_fused_kernel(
    const float* __restrict__ xin,     // x [N,16] (both layers; layer2 uses it for h1)
    const float* __restrict__ agg_in,  // layer2: agg1
    const int*   __restrict__ cnt_dst, // layer2: in-degree
    const float* __restrict__ rootp,   // layer2: root1
    const float* __restrict__ biasp,   // layer2: bias1
    float*       __restrict__ h1_out,  // layer2: h1 written here
    const float* __restrict__ ea,      // [E,8]
    const int2*  __restrict__ ord,     // [NG*CAP]
    const int*   __restrict__ cursor,  // [NG] bucket counts
    const float* __restrict__ w1,      // [8,16]
    const float* __restrict__ b1,      // [16]
    const float* __restrict__ w2,      // [16,256]
    const float* __restrict__ b2,      // [256]
    float*       __restrict__ agg_out) // [N,16] atomic accumulator
{
    __shared__ float xl[16 * 16];
    __shared__ float Yl[16 * YSTRIDE];

    int tid = threadIdx.x;
    int n0 = blockIdx.x * 16;
    int node = tid >> 4, o = tid & 15;

    // ---- stage input rows (layer2: compute h1 inline, fusing old node1 kernel)
    if (!SECOND) {
        xl[tid] = xin[(size_t)(n0 + node) * 16 + o];
    } else {
        float xo = xin[(size_t)(n0 + node) * 16 + o];
        int c = cnt_dst[n0 + node];
        float acc = agg_in[(size_t)(n0 + node) * 16 + o] / (float)(c > 0 ? c : 1)
                  + biasp[o];
#pragma unroll
        for (int i = 0; i < 16; ++i)
            acc += __shfl(xo, i, 16) * rootp[i * 16 + o];
        float h = fmaxf(acc, 0.0f);
        xl[tid] = h;
        h1_out[(size_t)(n0 + node) * 16 + o] = h;
    }
    __syncthreads();

    // ---- phase 1a: Y slices k=0..15; thread (k,o) keeps its 16 weights in regs
    {
        int k = tid >> 4;
        float w[16];
#pragma unroll
        for (int i = 0; i < 16; ++i) w[i] = w2[k * 256 + i * 16 + o];
#pragma unroll 4
        for (int nd = 0; nd < 16; ++nd) {
            const float4* xr = (const float4*)&xl[nd * 16];
            float4 x0 = xr[0], x1 = xr[1], x2 = xr[2], x3 = xr[3];
            float acc = x0.x * w[0] + x0.y * w[1] + x0.z * w[2] + x0.w * w[3]
                      + x1.x * w[4] + x1.y * w[5] + x1.z * w[6] + x1.w * w[7]
                      + x2.x * w[8] + x2.y * w[9] + x2.z * w[10] + x2.w * w[11]
                      + x3.x * w[12] + x3.y * w[13] + x3.z * w[14] + x3.w * w[15];
            Yl[nd * YSTRIDE + k * 16 + o] = acc;
        }
    }
    // ---- phase 1b: Y0 slice (b2); thread (node,o)
    {
        float w[16];
#pragma unroll
        for (int i = 0; i < 16; ++i) w[i] = b2[i * 16 + o];
        const float4* xr = (const float4*)&xl[node * 16];
        float4 x0 = xr[0], x1 = xr[1], x2 = xr[2], x3 = xr[3];
        float acc = x0.x * w[0] + x0.y * w[1] + x0.z * w[2] + x0.w * w[3]
                  + x1.x * w[4] + x1.y * w[5] + x1.z * w[6] + x1.w * w[7]
                  + x2.x * w[8] + x2.y * w[9] + x2.z * w[10] + x2.w * w[11]
                  + x3.x * w[12] + x3.y * w[13] + x3.z * w[14] + x3.w * w[15];
        Yl[node * YSTRIDE + 256 + o] = acc;
    }
    __syncthreads();

    // ---- phase 2: one thread per bucket slot
    int cnt = cursor[blockIdx.x];
    if (cnt > CAP) cnt = CAP;
    const int2* op = ord + (size_t)blockIdx.x * CAP;
    for (int j = tid; j < cnt; j += 256) {
        int2 od = op[j];
        int e = od.x;
        int d = od.y & 0x07FFFFFF;
        int nl = ((unsigned)od.y) >> 27;

        const float4* av = (const float4*)(ea + (size_t)e * 8);
        float4 a0 = av[0], a1 = av[1];
        float a[8] = {a0.x, a0.y, a0.z, a0.w, a1.x, a1.y, a1.z, a1.w};

        float hid[16];
#pragma unroll
        for (int jj = 0; jj < 16; ++jj) hid[jj] = b1[jj];
#pragma unroll
        for (int c = 0; c < 8; ++c)
#pragma unroll
            for (int jj = 0; jj < 16; ++jj) hid[jj] += a[c] * w1[c * 16 + jj];
#pragma unroll
        for (int jj = 0; jj < 16; ++jj) hid[jj] = fmaxf(hid[jj], 0.0f);

        const float4* Yr = (const float4*)&Yl[nl * YSTRIDE];
        float4 m0 = Yr[64], m1 = Yr[65], m2 = Yr[66], m3 = Yr[67];  // Y0
#pragma unroll
        for (int k = 0; k < 16; ++k) {
            float hk = hid[k];
            float4 y0 = Yr[k * 4 + 0], y1 = Yr[k * 4 + 1];
            float4 y2 = Yr[k * 4 + 2], y3 = Yr[k * 4 + 3];
            m0.x = fmaf(hk, y0.x, m0.x); m0.y = fmaf(hk, y0.y, m0.y);
            m0.z = fmaf(hk, y0.z, m0.z); m0.w = fmaf(hk, y0.w, m0.w);
            m1.x = fmaf(hk, y1.x, m1.x); m1.y = fmaf(hk, y1.y, m1.y);
            m1.z = fmaf(hk, y1.z, m1.z); m1.w = fmaf(hk, y1.w, m1.w);
            m2.x = fmaf(hk, y2.x, m2.x); m2.y = fmaf(hk, y2.y, m2.y);
            m2.z = fmaf(hk, y2.z, m2.z); m2.w = fmaf(hk, y2.w, m2.w);
            m3.x = fmaf(hk, y3.x, m3.x); m3.y = fmaf(hk, y3.y, m3.y);
            m3.z = fmaf(hk, y3.z, m3.z); m3.w = fmaf(hk, y3.w, m3.w);
        }
        float* ap = agg_out + (size_t)d * 16;
        unsafeAtomicAdd(ap + 0,  m0.x); unsafeAtomicAdd(ap + 1,  m0.y);
        unsafeAtomicAdd(ap + 2,  m0.z); unsafeAtomicAdd(ap + 3,  m0.w);
        unsafeAtomicAdd(ap + 4,  m1.x); unsafeAtomicAdd(ap + 5,  m1.y);
        unsafeAtomicAdd(ap + 6,  m1.z); unsafeAtomicAdd(ap + 7,  m1.w);
        unsafeAtomicAdd(ap + 8,  m2.x); unsafeAtomicAdd(ap + 9,  m2.y);
        unsafeAtomicAdd(ap + 10, m2.z); unsafeAtomicAdd(ap + 11, m2.w);
        unsafeAtomicAdd(ap + 12, m3.x); unsafeAtomicAdd(ap + 13, m3.y);
        unsafeAtomicAdd(ap + 14, m3.z); unsafeAtomicAdd(ap + 15, m3.w);
    }
}

// ---------------------------------------------------------------------------
// Final node kernel: layer-2 update (agg2/cnt + h1@root2 + b2, relu) + q head.
// 16 lanes per node, lane o = channel o.
// ---------------------------------------------------------------------------
__global__ __launch_bounds__(256) void node2q_kernel(
    const float* __restrict__ h1, const float* __restrict__ agg2,
    const int* __restrict__ cnt_dst,
    const float* __restrict__ root, const float* __restrict__ bias,
    const float* __restrict__ qw, const float* __restrict__ qb,
    float* __restrict__ out)
{
    int t = blockIdx.x * 256 + threadIdx.x;
    int n = t >> 4, o = t & 15;
    if (n >= NN) return;

    int c = cnt_dst[n];
    float acc = agg2[(size_t)n * 16 + o] / (float)(c > 0 ? c : 1) + bias[o];
    float ho = h1[(size_t)n * 16 + o];
#pragma unroll
    for (int i = 0; i < 16; ++i)
        acc += __shfl(ho, i, 16) * root[i * 16 + o];

    float q = fmaxf(acc, 0.0f) * qw[o];
#pragma unroll
    for (int d = 8; d >= 1; d >>= 1) q += __shfl_down(q, d, 16);
    if (o == 0) out[n] = q + qb[0];
}

extern "C" void kernel_launch(void* const* d_in, const int* in_sizes, int n_in,
                              void* d_out, int out_size, void* d_ws, size_t ws_size,
                              hipStream_t stream) {
    const float* x     = (const float*)d_in[0];
    const float* ea    = (const float*)d_in[1];
    const float* e1w1  = (const float*)d_in[2];
    const float* e1b1  = (const float*)d_in[3];
    const float* e1w2  = (const float*)d_in[4];
    const float* e1b2  = (const float*)d_in[5];
    const float* root1 = (const float*)d_in[6];
    const float* bias1 = (const float*)d_in[7];
    const float* e2w1  = (const float*)d_in[8];
    const float* e2b1  = (const float*)d_in[9];
    const float* e2w2  = (const float*)d_in[10];
    const float* e2b2  = (const float*)d_in[11];
    const float* root2 = (const float*)d_in[12];
    const float* bias2 = (const float*)d_in[13];
    const float* qw    = (const float*)d_in[14];
    const float* qb    = (const float*)d_in[15];
    const int*   eidx  = (const int*)d_in[16];

    float* agg1    = (float*)d_ws;                       // 16*NN
    float* agg2    = agg1 + (size_t)16 * NN;             // 16*NN
    int*   cursor  = (int*)(agg2 + (size_t)16 * NN);     // NG
    int*   cnt_dst = cursor + NG;                        // NN
    int2*  ord     = (int2*)(cnt_dst + NN + 1);          // NG*CAP (+1 pad: 8B align)
    float* h1      = (float*)(ord + (size_t)NG * CAP);   // 16*NN

    int eblocks = (NE + 255) / 256;  // 1563

    // zero region: agg1 | agg2 | cursor | cnt_dst (contiguous)
    size_t zero_bytes = ((size_t)32 * NN + NG + NN) * sizeof(int);
    hipMemsetAsync(d_ws, 0, zero_bytes, stream);

    fill_hist_kernel<<<eblocks, 256, 0, stream>>>(eidx, cursor, cnt_dst, ord);

    edge_fused_kernel<false><<<NG, 256, 0, stream>>>(
        x, nullptr, nullptr, nullptr, nullptr, nullptr,
        ea, ord, cursor, e1w1, e1b1, e1w2, e1b2, agg1);

    edge_fused_kernel<true><<<NG, 256, 0, stream>>>(
        x, agg1, cnt_dst, root1, bias1, h1,
        ea, ord, cursor, e2w1, e2b1, e2w2, e2b2, agg2);

    node2q_kernel<<<3125, 256, 0, stream>>>(
        h1, agg2, cnt_dst, root2, bias2, qw, qb, (float*)d_out);
}

// Round 2
// 279.617 us; speedup vs baseline: 3.0150x; 3.0150x over previous
//
#include <hip/hip_runtime.h>

#define NN 50000
#define NE 400000
#define NG (NN / 16)        // 3125 groups of 16 consecutive nodes
#define CAP 320             // bucket capacity: mean 128, sigma 11.3 -> 17-sigma margin
#define YSTRIDE 276         // 272 + pad (b128 align, spreads banks)

// ws layout (bytes):
//   msg   float [NG*CAP*16]   64.0 MB   (dst-bucket slot order)
//   h1    float [16*NN]        3.2 MB
//   cur_src int [NG]           zeroed
//   cur_dst int [NG]           zeroed
//   dloc  u8   [NG*CAP]        1.0 MB   (dst-local nibble per dst slot)
//   ord   int2 [NG*CAP]        8.0 MB   (src-bucket: {eid, pd | src_local<<20})

// ---------------------------------------------------------------------------
// One pass over edges: src-group bucket + dst-group slot assignment.
// ---------------------------------------------------------------------------
__global__ __launch_bounds__(256) void fill_kernel(
    const int* __restrict__ eidx, int* __restrict__ cur_src,
    int* __restrict__ cur_dst, int2* __restrict__ ord,
    unsigned char* __restrict__ dloc)
{
    int e = blockIdx.x * 256 + threadIdx.x;
    if (e < NE) {
        int s = eidx[e], d = eidx[NE + e];
        int gs = s >> 4, gd = d >> 4;
        int ss = atomicAdd(&cur_src[gs], 1);
        int sd = atomicAdd(&cur_dst[gd], 1);
        if (ss < CAP && sd < CAP) {   // statistically impossible to overflow
            int pd = gd * CAP + sd;   // global dst slot, < 2^20
            ord[(size_t)gs * CAP + ss] = make_int2(e, pd | ((s & 15) << 20));
            dloc[pd] = (unsigned char)(d & 15);
        }
    }
}

// ---------------------------------------------------------------------------
// Edge kernel. Block = group of 16 src nodes.
// Phase 1: Y[node][k][o] = sum_i in[node,i]*w2[k,i,o] in LDS; Y0 (b2) at 256.
// Phase 2: thread per src-bucket slot: hid = relu(ea[e]@w1+b1);
//          msg = Y0 + sum_k hid[k]*Y[k]; plain float4 stores to msg[pd].
// ---------------------------------------------------------------------------
__global__ __launch_bounds__(256) void edge_fused_kernel(
    const float* __restrict__ xin,     // layer input [N,16] (x or h1)
    const float* __restrict__ ea,      // [E,8]
    const int2*  __restrict__ ord,     // [NG*CAP]
    const int*   __restrict__ cur_src, // [NG] bucket counts
    const float* __restrict__ w1,      // [8,16]
    const float* __restrict__ b1,      // [16]
    const float* __restrict__ w2,      // [16,256]
    const float* __restrict__ b2,      // [256]
    float*       __restrict__ msg)     // [NG*CAP,16] dst-slot order
{
    __shared__ float xl[16 * 16];
    __shared__ float Yl[16 * YSTRIDE];

    int tid = threadIdx.x;
    int n0 = blockIdx.x * 16;
    int node = tid >> 4, o = tid & 15;

    xl[tid] = xin[(size_t)(n0 + node) * 16 + o];
    __syncthreads();

    // ---- phase 1a: Y slices k=0..15; thread (k,o) keeps its 16 weights in regs
    {
        int k = tid >> 4;
        float w[16];
#pragma unroll
        for (int i = 0; i < 16; ++i) w[i] = w2[k * 256 + i * 16 + o];
#pragma unroll 4
        for (int nd = 0; nd < 16; ++nd) {
            const float4* xr = (const float4*)&xl[nd * 16];
            float4 x0 = xr[0], x1 = xr[1], x2 = xr[2], x3 = xr[3];
            float acc = x0.x * w[0] + x0.y * w[1] + x0.z * w[2] + x0.w * w[3]
                      + x1.x * w[4] + x1.y * w[5] + x1.z * w[6] + x1.w * w[7]
                      + x2.x * w[8] + x2.y * w[9] + x2.z * w[10] + x2.w * w[11]
                      + x3.x * w[12] + x3.y * w[13] + x3.z * w[14] + x3.w * w[15];
            Yl[nd * YSTRIDE + k * 16 + o] = acc;
        }
    }
    // ---- phase 1b: Y0 slice (b2); thread (node,o)
    {
        float w[16];
#pragma unroll
        for (int i = 0; i < 16; ++i) w[i] = b2[i * 16 + o];
        const float4* xr = (const float4*)&xl[node * 16];
        float4 x0 = xr[0], x1 = xr[1], x2 = xr[2], x3 = xr[3];
        float acc = x0.x * w[0] + x0.y * w[1] + x0.z * w[2] + x0.w * w[3]
                  + x1.x * w[4] + x1.y * w[5] + x1.z * w[6] + x1.w * w[7]
                  + x2.x * w[8] + x2.y * w[9] + x2.z * w[10] + x2.w * w[11]
                  + x3.x * w[12] + x3.y * w[13] + x3.z * w[14] + x3.w * w[15];
        Yl[node * YSTRIDE + 256 + o] = acc;
    }
    __syncthreads();

    // ---- phase 2: one thread per bucket slot
    int cnt = cur_src[blockIdx.x];
    if (cnt > CAP) cnt = CAP;
    const int2* op = ord + (size_t)blockIdx.x * CAP;
    for (int j = tid; j < cnt; j += 256) {
        int2 od = op[j];
        int e  = od.x;
        int pd = od.y & 0xFFFFF;
        int nl = (od.y >> 20) & 15;

        const float4* av = (const float4*)(ea + (size_t)e * 8);
        float4 a0 = av[0], a1 = av[1];
        float a[8] = {a0.x, a0.y, a0.z, a0.w, a1.x, a1.y, a1.z, a1.w};

        float hid[16];
#pragma unroll
        for (int jj = 0; jj < 16; ++jj) hid[jj] = b1[jj];
#pragma unroll
        for (int c = 0; c < 8; ++c)
#pragma unroll
            for (int jj = 0; jj < 16; ++jj) hid[jj] += a[c] * w1[c * 16 + jj];
#pragma unroll
        for (int jj = 0; jj < 16; ++jj) hid[jj] = fmaxf(hid[jj], 0.0f);

        const float4* Yr = (const float4*)&Yl[nl * YSTRIDE];
        float4 m0 = Yr[64], m1 = Yr[65], m2 = Yr[66], m3 = Yr[67];  // Y0
#pragma unroll
        for (int k = 0; k < 16; ++k) {
            float hk = hid[k];
            float4 y0 = Yr[k * 4 + 0], y1 = Yr[k * 4 + 1];
            float4 y2 = Yr[k * 4 + 2], y3 = Yr[k * 4 + 3];
            m0.x = fmaf(hk, y0.x, m0.x); m0.y = fmaf(hk, y0.y, m0.y);
            m0.z = fmaf(hk, y0.z, m0.z); m0.w = fmaf(hk, y0.w, m0.w);
            m1.x = fmaf(hk, y1.x, m1.x); m1.y = fmaf(hk, y1.y, m1.y);
            m1.z = fmaf(hk, y1.z, m1.z); m1.w = fmaf(hk, y1.w, m1.w);
            m2.x = fmaf(hk, y2.x, m2.x); m2.y = fmaf(hk, y2.y, m2.y);
            m2.z = fmaf(hk, y2.z, m2.z); m2.w = fmaf(hk, y2.w, m2.w);
            m3.x = fmaf(hk, y3.x, m3.x); m3.y = fmaf(hk, y3.y, m3.y);
            m3.z = fmaf(hk, y3.z, m3.z); m3.w = fmaf(hk, y3.w, m3.w);
        }
        float4* mp = (float4*)(msg + (size_t)pd * 16);
        mp[0] = m0; mp[1] = m1; mp[2] = m2; mp[3] = m3;
    }
}

// ---------------------------------------------------------------------------
// Gather kernel. Block = group of 16 dst nodes. Streams the group's msg slots
// (coalesced), accumulates into a 16x16 LDS tile via ds_add_f32, counts
// in-degree from the same loop, then applies the NNConv update.
// SECOND=false: out = h1 = relu(mean + x@root + bias)
// SECOND=true : out[n] = relu(mean + h1@root + bias) @ qw + qb
// ---------------------------------------------------------------------------
template <bool SECOND>
__global__ __launch_bounds__(256) void gather_kernel(
    const float* __restrict__ xin,     // layer input for root transform
    const float* __restrict__ msg,
    const int*   __restrict__ cur_dst,
    const unsigned char* __restrict__ dloc,
    const float* __restrict__ root, const float* __restrict__ bias,
    const float* __restrict__ qw, const float* __restrict__ qb,
    float* __restrict__ outp)
{
    __shared__ float acc[16 * 16];
    __shared__ int cntl[16];
    int tid = threadIdx.x, gd = blockIdx.x;
    int node = tid >> 4, o = tid & 15;

    acc[tid] = 0.0f;
    if (tid < 16) cntl[tid] = 0;
    __syncthreads();

    int cnt = cur_dst[gd];
    if (cnt > CAP) cnt = CAP;
    const float* mp = msg + (size_t)gd * CAP * 16;
    const unsigned char* dl = dloc + (size_t)gd * CAP;
    for (int j = node; j < cnt; j += 16) {
        int dn = dl[j];
        float v = mp[j * 16 + o];
        atomicAdd(&acc[dn * 16 + o], v);      // ds_add_f32
        if (o == 0) atomicAdd(&cntl[dn], 1);
    }
    __syncthreads();

    int n = gd * 16 + node;
    int c = cntl[node];
    float a = acc[node * 16 + o] / (float)(c > 0 ? c : 1) + bias[o];
    float xo = xin[(size_t)n * 16 + o];
#pragma unroll
    for (int i = 0; i < 16; ++i)
        a += __shfl(xo, i, 16) * root[i * 16 + o];
    float h = fmaxf(a, 0.0f);

    if (!SECOND) {
        outp[(size_t)n * 16 + o] = h;
    } else {
        float q = h * qw[o];
#pragma unroll
        for (int dd = 8; dd >= 1; dd >>= 1) q += __shfl_down(q, dd, 16);
        if (o == 0) outp[n] = q + qb[0];
    }
}

extern "C" void kernel_launch(void* const* d_in, const int* in_sizes, int n_in,
                              void* d_out, int out_size, void* d_ws, size_t ws_size,
                              hipStream_t stream) {
    const float* x     = (const float*)d_in[0];
    const float* ea    = (const float*)d_in[1];
    const float* e1w1  = (const float*)d_in[2];
    const float* e1b1  = (const float*)d_in[3];
    const float* e1w2  = (const float*)d_in[4];
    const float* e1b2  = (const float*)d_in[5];
    const float* root1 = (const float*)d_in[6];
    const float* bias1 = (const float*)d_in[7];
    const float* e2w1  = (const float*)d_in[8];
    const float* e2b1  = (const float*)d_in[9];
    const float* e2w2  = (const float*)d_in[10];
    const float* e2b2  = (const float*)d_in[11];
    const float* root2 = (const float*)d_in[12];
    const float* bias2 = (const float*)d_in[13];
    const float* qw    = (const float*)d_in[14];
    const float* qb    = (const float*)d_in[15];
    const int*   eidx  = (const int*)d_in[16];

    float* msg     = (float*)d_ws;                         // NG*CAP*16 floats
    float* h1      = msg + (size_t)NG * CAP * 16;          // 16*NN
    int*   cur_src = (int*)(h1 + (size_t)16 * NN);         // NG  (zeroed)
    int*   cur_dst = cur_src + NG;                         // NG  (zeroed)
    unsigned char* dloc = (unsigned char*)(cur_dst + NG);  // NG*CAP bytes
    int2*  ord     = (int2*)(dloc + (size_t)NG * CAP);     // NG*CAP int2

    int eblocks = (NE + 255) / 256;  // 1563

    hipMemsetAsync(cur_src, 0, (size_t)2 * NG * sizeof(int), stream);

    fill_kernel<<<eblocks, 256, 0, stream>>>(eidx, cur_src, cur_dst, ord, dloc);

    // --- layer 1 ---
    edge_fused_kernel<<<NG, 256, 0, stream>>>(x, ea, ord, cur_src,
                                              e1w1, e1b1, e1w2, e1b2, msg);
    gather_kernel<false><<<NG, 256, 0, stream>>>(x, msg, cur_dst, dloc,
                                                 root1, bias1, qw, qb, h1);

    // --- layer 2 + q head ---
    edge_fused_kernel<<<NG, 256, 0, stream>>>(h1, ea, ord, cur_src,
                                              e2w1, e2b1, e2w2, e2b2, msg);
    gather_kernel<true><<<NG, 256, 0, stream>>>(h1, msg, cur_dst, dloc,
                                                root2, bias2, qw, qb,
                                                (float*)d_out);
}

// Round 3
// 209.324 us; speedup vs baseline: 4.0274x; 1.3358x over previous
//
#include <hip/hip_runtime.h>

#define NN 50000
#define NE 400000
#define NG (NN / 16)        // 3125 blocks of 16 consecutive nodes
#define SCAP 40             // per-node out-edge capacity (mean 8, Poisson tail ~1e-14)
#define DCAP 36             // per-node in-edge capacity  (mean 8, Poisson tail ~5e-12)
#define YSTRIDE 276         // 272 + pad (b128 align, spreads banks)

// ws layout (bytes):
//   msg1  float [NN*DCAP*16]  115.2 MB  (layer-1 messages, per-dst-node slots)
//   msg2  float [NN*DCAP*16]  115.2 MB  (layer-2 messages)
//   h1    float [16*NN]         3.2 MB
//   cur_src int [NN]          200 KB (zeroed)
//   cur_dst int [NN]          200 KB (zeroed)
//   ord   int2  [NN*SCAP]      16.0 MB  {eid, dst slot pd}

// ---------------------------------------------------------------------------
// One pass over edges: per-node src slot + per-node dst slot. Only write is
// 8 B ord per edge; counters spread over 50k addresses (low contention).
// ---------------------------------------------------------------------------
__global__ __launch_bounds__(256) void fill_kernel(
    const int* __restrict__ eidx, int* __restrict__ cur_src,
    int* __restrict__ cur_dst, int2* __restrict__ ord)
{
    int e = blockIdx.x * 256 + threadIdx.x;
    if (e < NE) {
        int s = eidx[e], d = eidx[NE + e];
        int ss = atomicAdd(&cur_src[s], 1);
        int sd = atomicAdd(&cur_dst[d], 1);
        if (ss < SCAP && sd < DCAP)   // statistically impossible to overflow
            ord[(size_t)s * SCAP + ss] = make_int2(e, d * DCAP + sd);
    }
}

// ---------------------------------------------------------------------------
// Edge kernel. Block = 16 consecutive src nodes.
// SECOND=true: staging fuses the layer-1 gather: h1 = relu(mean(msg1 range)
//              + x@root1 + bias1) computed in-register for the block's own
//              16 nodes (per-node dst slots make this block-local), written
//              to global once and used as the layer input.
// Phase 1: Y[node][k][o] = sum_i in[node,i]*w2[k,i,o] in LDS; Y0 (b2) at 256.
// Phase 2: thread per out-edge: hid = relu(ea[e]@w1+b1);
//          msg = Y0 + sum_k hid[k]*Y[k]; plain float4 stores to mout[pd].
// ---------------------------------------------------------------------------
template <bool SECOND>
__global__ __launch_bounds__(256) void edge_fused_kernel(
    const float* __restrict__ xin,     // x [N,16]
    const float* __restrict__ min_,    // SECOND: msg1
    const int*   __restrict__ cur_dst, // SECOND: in-degree
    const float* __restrict__ rootp,   // SECOND: root1
    const float* __restrict__ biasp,   // SECOND: bias1
    float*       __restrict__ h1_out,  // SECOND: h1 written here
    const float* __restrict__ ea,      // [E,8]
    const int2*  __restrict__ ord,     // [NN*SCAP]
    const int*   __restrict__ cur_src, // [NN]
    const float* __restrict__ w1,      // [8,16]
    const float* __restrict__ b1,      // [16]
    const float* __restrict__ w2,      // [16,256]
    const float* __restrict__ b2,      // [256]
    float*       __restrict__ mout)    // [NN*DCAP,16]
{
    __shared__ float xl[16 * 16];
    __shared__ float Yl[16 * YSTRIDE];
    __shared__ int scnt[16];
    __shared__ int so[17];

    int tid = threadIdx.x;
    int n0 = blockIdx.x * 16;
    int node = tid >> 4, o = tid & 15;
    int n = n0 + node;

    // ---- stage input rows (layer2: fused gather1 + node update)
    if (!SECOND) {
        xl[tid] = xin[(size_t)n * 16 + o];
    } else {
        int craw = cur_dst[n];
        int cnt = craw < DCAP ? craw : DCAP;
        const float* mp = min_ + (size_t)n * DCAP * 16;
        float sum = 0.0f;
        for (int j = 0; j < cnt; ++j) sum += mp[j * 16 + o];
        float acc = sum / (float)(craw > 0 ? craw : 1) + biasp[o];
        float xo = xin[(size_t)n * 16 + o];
#pragma unroll
        for (int i = 0; i < 16; ++i)
            acc += __shfl(xo, i, 16) * rootp[i * 16 + o];
        float h = fmaxf(acc, 0.0f);
        xl[tid] = h;
        h1_out[(size_t)n * 16 + o] = h;
    }
    if (tid < 16) {
        int c = cur_src[n0 + tid];
        scnt[tid] = c < SCAP ? c : SCAP;
    }
    __syncthreads();

    if (tid == 0) {
        int s = 0;
#pragma unroll
        for (int t = 0; t < 16; ++t) { so[t] = s; s += scnt[t]; }
        so[16] = s;
    }

    // ---- phase 1a: Y slices k=0..15; thread (k,o) keeps its 16 weights in regs
    {
        int k = tid >> 4;
        float w[16];
#pragma unroll
        for (int i = 0; i < 16; ++i) w[i] = w2[k * 256 + i * 16 + o];
#pragma unroll 4
        for (int nd = 0; nd < 16; ++nd) {
            const float4* xr = (const float4*)&xl[nd * 16];
            float4 x0 = xr[0], x1 = xr[1], x2 = xr[2], x3 = xr[3];
            float acc = x0.x * w[0] + x0.y * w[1] + x0.z * w[2] + x0.w * w[3]
                      + x1.x * w[4] + x1.y * w[5] + x1.z * w[6] + x1.w * w[7]
                      + x2.x * w[8] + x2.y * w[9] + x2.z * w[10] + x2.w * w[11]
                      + x3.x * w[12] + x3.y * w[13] + x3.z * w[14] + x3.w * w[15];
            Yl[nd * YSTRIDE + k * 16 + o] = acc;
        }
    }
    // ---- phase 1b: Y0 slice (b2); thread (node,o)
    {
        float w[16];
#pragma unroll
        for (int i = 0; i < 16; ++i) w[i] = b2[i * 16 + o];
        const float4* xr = (const float4*)&xl[node * 16];
        float4 x0 = xr[0], x1 = xr[1], x2 = xr[2], x3 = xr[3];
        float acc = x0.x * w[0] + x0.y * w[1] + x0.z * w[2] + x0.w * w[3]
                  + x1.x * w[4] + x1.y * w[5] + x1.z * w[6] + x1.w * w[7]
                  + x2.x * w[8] + x2.y * w[9] + x2.z * w[10] + x2.w * w[11]
                  + x3.x * w[12] + x3.y * w[13] + x3.z * w[14] + x3.w * w[15];
        Yl[node * YSTRIDE + 256 + o] = acc;
    }
    __syncthreads();

    // ---- phase 2: one thread per out-edge of the block's 16 nodes
    int total = so[16];
    for (int j = tid; j < total; j += 256) {
        int nd = 0;
#pragma unroll
        for (int t = 1; t < 16; ++t) nd += (j >= so[t]) ? 1 : 0;
        int local = j - so[nd];

        int2 od = ord[(size_t)(n0 + nd) * SCAP + local];
        int e = od.x, pd = od.y;

        const float4* av = (const float4*)(ea + (size_t)e * 8);
        float4 a0 = av[0], a1 = av[1];
        float a[8] = {a0.x, a0.y, a0.z, a0.w, a1.x, a1.y, a1.z, a1.w};

        float hid[16];
#pragma unroll
        for (int jj = 0; jj < 16; ++jj) hid[jj] = b1[jj];
#pragma unroll
        for (int c = 0; c < 8; ++c)
#pragma unroll
            for (int jj = 0; jj < 16; ++jj) hid[jj] += a[c] * w1[c * 16 + jj];
#pragma unroll
        for (int jj = 0; jj < 16; ++jj) hid[jj] = fmaxf(hid[jj], 0.0f);

        const float4* Yr = (const float4*)&Yl[nd * YSTRIDE];
        float4 m0 = Yr[64], m1 = Yr[65], m2 = Yr[66], m3 = Yr[67];  // Y0
#pragma unroll
        for (int k = 0; k < 16; ++k) {
            float hk = hid[k];
            float4 y0 = Yr[k * 4 + 0], y1 = Yr[k * 4 + 1];
            float4 y2 = Yr[k * 4 + 2], y3 = Yr[k * 4 + 3];
            m0.x = fmaf(hk, y0.x, m0.x); m0.y = fmaf(hk, y0.y, m0.y);
            m0.z = fmaf(hk, y0.z, m0.z); m0.w = fmaf(hk, y0.w, m0.w);
            m1.x = fmaf(hk, y1.x, m1.x); m1.y = fmaf(hk, y1.y, m1.y);
            m1.z = fmaf(hk, y1.z, m1.z); m1.w = fmaf(hk, y1.w, m1.w);
            m2.x = fmaf(hk, y2.x, m2.x); m2.y = fmaf(hk, y2.y, m2.y);
            m2.z = fmaf(hk, y2.z, m2.z); m2.w = fmaf(hk, y2.w, m2.w);
            m3.x = fmaf(hk, y3.x, m3.x); m3.y = fmaf(hk, y3.y, m3.y);
            m3.z = fmaf(hk, y3.z, m3.z); m3.w = fmaf(hk, y3.w, m3.w);
        }
        float4* mp = (float4*)(mout + (size_t)pd * 16);
        mp[0] = m0; mp[1] = m1; mp[2] = m2; mp[3] = m3;
    }
}

// ---------------------------------------------------------------------------
// Final node kernel: mean over own msg2 range (register accumulation, no LDS),
// layer-2 update + q head. 16 lanes per node.
// ---------------------------------------------------------------------------
__global__ __launch_bounds__(256) void node2q_kernel(
    const float* __restrict__ h1, const float* __restrict__ msg2,
    const int* __restrict__ cur_dst,
    const float* __restrict__ root, const float* __restrict__ bias,
    const float* __restrict__ qw, const float* __restrict__ qb,
    float* __restrict__ out)
{
    int t = blockIdx.x * 256 + threadIdx.x;
    int n = t >> 4, o = t & 15;
    if (n >= NN) return;

    int craw = cur_dst[n];
    int cnt = craw < DCAP ? craw : DCAP;
    const float* mp = msg2 + (size_t)n * DCAP * 16;
    float sum = 0.0f;
    for (int j = 0; j < cnt; ++j) sum += mp[j * 16 + o];
    float acc = sum / (float)(craw > 0 ? craw : 1) + bias[o];

    float ho = h1[(size_t)n * 16 + o];
#pragma unroll
    for (int i = 0; i < 16; ++i)
        acc += __shfl(ho, i, 16) * root[i * 16 + o];

    float q = fmaxf(acc, 0.0f) * qw[o];
#pragma unroll
    for (int d = 8; d >= 1; d >>= 1) q += __shfl_down(q, d, 16);
    if (o == 0) out[n] = q + qb[0];
}

extern "C" void kernel_launch(void* const* d_in, const int* in_sizes, int n_in,
                              void* d_out, int out_size, void* d_ws, size_t ws_size,
                              hipStream_t stream) {
    const float* x     = (const float*)d_in[0];
    const float* ea    = (const float*)d_in[1];
    const float* e1w1  = (const float*)d_in[2];
    const float* e1b1  = (const float*)d_in[3];
    const float* e1w2  = (const float*)d_in[4];
    const float* e1b2  = (const float*)d_in[5];
    const float* root1 = (const float*)d_in[6];
    const float* bias1 = (const float*)d_in[7];
    const float* e2w1  = (const float*)d_in[8];
    const float* e2b1  = (const float*)d_in[9];
    const float* e2w2  = (const float*)d_in[10];
    const float* e2b2  = (const float*)d_in[11];
    const float* root2 = (const float*)d_in[12];
    const float* bias2 = (const float*)d_in[13];
    const float* qw    = (const float*)d_in[14];
    const float* qb    = (const float*)d_in[15];
    const int*   eidx  = (const int*)d_in[16];

    float* msg1    = (float*)d_ws;                          // NN*DCAP*16
    float* msg2    = msg1 + (size_t)NN * DCAP * 16;         // NN*DCAP*16
    float* h1      = msg2 + (size_t)NN * DCAP * 16;         // 16*NN
    int*   cur_src = (int*)(h1 + (size_t)16 * NN);          // NN (zeroed)
    int*   cur_dst = cur_src + NN;                          // NN (zeroed)
    int2*  ord     = (int2*)(cur_dst + NN);                 // NN*SCAP

    int eblocks = (NE + 255) / 256;  // 1563

    hipMemsetAsync(cur_src, 0, (size_t)2 * NN * sizeof(int), stream);

    fill_kernel<<<eblocks, 256, 0, stream>>>(eidx, cur_src, cur_dst, ord);

    // layer 1 edges
    edge_fused_kernel<false><<<NG, 256, 0, stream>>>(
        x, nullptr, nullptr, nullptr, nullptr, nullptr,
        ea, ord, cur_src, e1w1, e1b1, e1w2, e1b2, msg1);

    // layer 2 edges (+ fused layer-1 node update -> h1)
    edge_fused_kernel<true><<<NG, 256, 0, stream>>>(
        x, msg1, cur_dst, root1, bias1, h1,
        ea, ord, cur_src, e2w1, e2b1, e2w2, e2b2, msg2);

    // layer-2 node update + q head
    node2q_kernel<<<3125, 256, 0, stream>>>(
        h1, msg2, cur_dst, root2, bias2, qw, qb, (float*)d_out);
}